// Round 4
// baseline (439.551 us; speedup 1.0000x reference)
//
#include <hip/hip_runtime.h>
#include <hip/hip_bf16.h>

// GemmRS: out[m,n] = sum_{w,k} A[w,m,k]*B[w,n,k]
// A: [8,8192,512] f32, B: [8,1024,512] f32, out: [8192,1024] f32.
// Phase 1: convert A,B -> bf16 in d_ws.
// Phase 2: 32x32x16 bf16 MFMA. Block tile 256x128, 4 waves of 128x64 (4x2 acc).
//   A: LDS double-buffered (64 KB) via global_load_lds w=16, XOR-swizzled.
//   B: direct global->VGPR, register double-buffered, prefetched 1 iter ahead.
//   Raw s_barrier + s_waitcnt vmcnt(16) pipeline (R3-validated technique).
//   Grid 256 = 1 block/CU; m-tile fastest so A-panel sharers land on one XCD.

#define WS 8
#define MM 8192
#define KK 512
#define NN 1024
#define KTOT (WS * KK)  // 4096
#define BMt 256
#define BNt 128
#define BK 64
#define ITERS (KTOT / BK)  // 64

#define A_ELEMS ((size_t)WS * MM * KK)
#define B_ELEMS ((size_t)WS * NN * KK)
#define WS_NEEDED ((A_ELEMS + B_ELEMS) * 2)

typedef __attribute__((ext_vector_type(8))) short short8;
typedef __attribute__((ext_vector_type(4))) short short4v;
typedef __attribute__((ext_vector_type(4))) float floatx4;
typedef __attribute__((ext_vector_type(16))) float floatx16;

static __device__ inline short f2bf(float f) {
    union { __hip_bfloat16 h; short s; } u;
    u.h = __float2bfloat16(f);  // RNE
    return u.s;
}

static __device__ inline void glds16(const short* g, short* l) {
    __builtin_amdgcn_global_load_lds(
        (const __attribute__((address_space(1))) unsigned int*)(uintptr_t)g,
        (__attribute__((address_space(3))) unsigned int*)(uintptr_t)l,
        16, 0, 0);
}

// ---------------- Phase 1: f32 -> bf16 convert (streaming) ----------------
#define CVT_ABLOCKS 16384
#define CVT_NBLOCKS 18432

__global__ __launch_bounds__(256)
void cvt_f32_bf16(const float* __restrict__ A, const float* __restrict__ B,
                  short* __restrict__ Abf, short* __restrict__ Bbf) {
    const float* src;
    short* dst;
    size_t base;
    if (blockIdx.x < CVT_ABLOCKS) {
        src = A; dst = Abf;
        base = ((size_t)blockIdx.x * 256 + threadIdx.x) * 8;
    } else {
        src = B; dst = Bbf;
        base = ((size_t)(blockIdx.x - CVT_ABLOCKS) * 256 + threadIdx.x) * 8;
    }
    float4 v0 = *(const float4*)(src + base);
    float4 v1 = *(const float4*)(src + base + 4);
    short8 o = { f2bf(v0.x), f2bf(v0.y), f2bf(v0.z), f2bf(v0.w),
                 f2bf(v1.x), f2bf(v1.y), f2bf(v1.z), f2bf(v1.w) };
    *(short8*)(dst + base) = o;
}

// ---------------- Phase 2: 32x32x16 GEMM, A-LDS + B-register pipeline ------
__global__ __launch_bounds__(256, 1)
void gemm_bf16_rs(const short* __restrict__ Abf, const short* __restrict__ Bbf,
                  float* __restrict__ C) {
    __shared__ short As[2][BMt * BK];  // 2 x 32 KB

    const int tid  = threadIdx.x;
    const int lane = tid & 63;
    const int wid  = tid >> 6;
    const int m0 = blockIdx.x * BMt;  // grid.x = 32 (m fastest -> XCD share A)
    const int n0 = blockIdx.y * BNt;  // grid.y = 8
    const int wr = wid >> 1, wc = wid & 1;  // wave tile: (wr*128, wc*64)
    const int l31   = lane & 31;
    const int khalf = lane >> 5;  // 0/1: which 8-elem half of K16

    // A staging: chunk = 64 lanes x 16B = 8 rows x 8 segs; XOR swizzle by row&7
    // (conflict-free fragment reads, verified 0 conflicts R2/R3).
    const int lrow = lane >> 3;
    const int ss   = (lane & 7) ^ lrow;
    size_t gA[8];
#pragma unroll
    for (int q = 0; q < 8; ++q)
        gA[q] = (size_t)(m0 + wid * 64 + q * 8 + lrow) * KK + ss * 8;

    const int nIdx = n0 + wc * 64 + l31;  // B row for j=0 (j=1: +32)

    floatx16 acc[4][2];
#pragma unroll
    for (int i = 0; i < 4; ++i)
#pragma unroll
        for (int j = 0; j < 2; ++j) acc[i][j] = (floatx16)0.f;

    short8 breg[2][2][4];  // [buf][j][kc]

    // Prologue: tile 0 (w=0, k=0): B -> breg[0], A -> As[0]
#pragma unroll
    for (int j = 0; j < 2; ++j)
#pragma unroll
        for (int kc = 0; kc < 4; ++kc)
            breg[0][j][kc] = *(const short8*)&Bbf[(size_t)(nIdx + j * 32) * KK +
                                                  kc * 16 + khalf * 8];
#pragma unroll
    for (int q = 0; q < 8; ++q)
        glds16(Abf + gA[q], &As[0][(wid * 8 + q) * 512 + lane * 8]);

    for (int t = 0; t < ITERS; ++t) {
        const int p  = t & 1;
        const int tn = (t + 1) & (ITERS - 1);  // wrap: redundant tile-0 prefetch
        const int np = tn & 1;
        const int wn = tn >> 3;
        const int kn = (tn & 7) * BK;
        const short* Aw = Abf + (size_t)wn * MM * KK + kn;
        const short* Bw = Bbf + (size_t)wn * NN * KK + kn;

        // Prefetch tile t+1: B into breg[np] (8 loads), A into As[np] (8 glds)
#pragma unroll
        for (int j = 0; j < 2; ++j)
#pragma unroll
            for (int kc = 0; kc < 4; ++kc)
                breg[np][j][kc] = *(const short8*)&Bw[(size_t)(nIdx + j * 32) * KK +
                                                      kc * 16 + khalf * 8];
#pragma unroll
        for (int q = 0; q < 8; ++q)
            glds16(Aw + gA[q], &As[np][(wid * 8 + q) * 512 + lane * 8]);

        // Wait for tile t's 16 loads (8 B + 8 glds); t+1's 16 stay in flight.
        asm volatile("s_waitcnt vmcnt(16)" ::: "memory");
        asm volatile("s_barrier" ::: "memory");

        // Compute tile t: 4 kc steps x (4 A-frag ds_reads + 8 MFMA)
#pragma unroll
        for (int kc = 0; kc < 4; ++kc) {
            short8 af[4];
#pragma unroll
            for (int i = 0; i < 4; ++i) {
                const int row = wr * 128 + i * 32 + l31;
                const int seg = (kc * 2 + khalf) ^ (lane & 7);  // row&7==lane&7
                af[i] = *(const short8*)&As[p][row * BK + seg * 8];
            }
#pragma unroll
            for (int i = 0; i < 4; ++i)
#pragma unroll
                for (int j = 0; j < 2; ++j)
                    acc[i][j] = __builtin_amdgcn_mfma_f32_32x32x16_bf16(
                        af[i], breg[p][j][kc], acc[i][j], 0, 0, 0);
        }

        // All LDS reads of As[p] consumed (MFMA reg deps) before next glds.
        asm volatile("s_barrier" ::: "memory");
    }

    // Epilogue: 32x32 C/D layout: col=lane&31, row=(r&3)+8*(r>>2)+4*(lane>>5)
#pragma unroll
    for (int i = 0; i < 4; ++i)
#pragma unroll
        for (int j = 0; j < 2; ++j) {
            const int n = n0 + wc * 64 + j * 32 + l31;
            const int mb = m0 + wr * 128 + i * 32 + 4 * khalf;
#pragma unroll
            for (int r = 0; r < 16; ++r) {
                const int m = mb + (r & 3) + 8 * (r >> 2);
                C[(size_t)m * NN + n] = acc[i][j][r];
            }
        }
}

// ---------------- Fallback (fused, ws too small) ----------------
__global__ __launch_bounds__(256, 2)
void gemm_rs_fused(const float* __restrict__ A, const float* __restrict__ B,
                   float* __restrict__ C) {
    __shared__ short Asf[128 * 32];
    __shared__ short Bsf[128 * 32];
    const int tid = threadIdx.x;
    const int m0 = blockIdx.y * 128;
    const int n0 = blockIdx.x * 128;
    const int wid = tid >> 6, lane = tid & 63;
    const int wr = wid >> 1, wc = wid & 1;
    const int lm = lane & 15, quad = lane >> 4;
    floatx4 acc[4][4];
#pragma unroll
    for (int i = 0; i < 4; ++i)
#pragma unroll
        for (int j = 0; j < 4; ++j) acc[i][j] = (floatx4)0.f;
    for (int kt = 0; kt < KTOT; kt += 32) {
        const int w = kt >> 9, kk = kt & (KK - 1);
        const float* Aw = A + (size_t)w * MM * KK;
        const float* Bw = B + (size_t)w * NN * KK;
        __syncthreads();
#pragma unroll
        for (int i = 0; i < 4; ++i) {
            const int idx = i * 256 + tid;
            const int row = idx >> 3;
            const int c4 = (idx & 7) * 4;
            float4 av = *(const float4*)&Aw[(size_t)(m0 + row) * KK + kk + c4];
            float4 bv = *(const float4*)&Bw[(size_t)(n0 + row) * KK + kk + c4];
            short4v a4 = { f2bf(av.x), f2bf(av.y), f2bf(av.z), f2bf(av.w) };
            short4v b4 = { f2bf(bv.x), f2bf(bv.y), f2bf(bv.z), f2bf(bv.w) };
            *(short4v*)&Asf[row * 32 + c4] = a4;
            *(short4v*)&Bsf[row * 32 + c4] = b4;
        }
        __syncthreads();
        short8 af[4], bfr[4];
#pragma unroll
        for (int i = 0; i < 4; ++i)
            af[i] = *(const short8*)&Asf[(wr * 64 + i * 16 + lm) * 32 + quad * 8];
#pragma unroll
        for (int j = 0; j < 4; ++j)
            bfr[j] = *(const short8*)&Bsf[(wc * 64 + j * 16 + lm) * 32 + quad * 8];
#pragma unroll
        for (int i = 0; i < 4; ++i)
#pragma unroll
            for (int j = 0; j < 4; ++j)
                acc[i][j] = __builtin_amdgcn_mfma_f32_16x16x32_bf16(
                    af[i], bfr[j], acc[i][j], 0, 0, 0);
    }
#pragma unroll
    for (int i = 0; i < 4; ++i)
#pragma unroll
        for (int j = 0; j < 4; ++j) {
            const int n = n0 + wc * 64 + j * 16 + lm;
#pragma unroll
            for (int r = 0; r < 4; ++r) {
                const int m = m0 + wr * 64 + i * 16 + quad * 4 + r;
                C[(size_t)m * NN + n] = acc[i][j][r];
            }
        }
}

extern "C" void kernel_launch(void* const* d_in, const int* in_sizes, int n_in,
                              void* d_out, int out_size, void* d_ws, size_t ws_size,
                              hipStream_t stream) {
    const float* A = (const float*)d_in[0];  // [8,8192,512]
    const float* B = (const float*)d_in[1];  // [8,1024,512]
    float* C = (float*)d_out;                // [8192,1024]

    if (ws_size >= WS_NEEDED) {
        short* Abf = (short*)d_ws;
        short* Bbf = Abf + A_ELEMS;
        cvt_f32_bf16<<<CVT_NBLOCKS, 256, 0, stream>>>(A, B, Abf, Bbf);
        dim3 grid(MM / BMt, NN / BNt);  // (32, 8) = 256 blocks, 1/CU
        gemm_bf16_rs<<<grid, 256, 0, stream>>>(Abf, Bbf, C);
    } else {
        dim3 grid(NN / 128, MM / 128);
        gemm_rs_fused<<<grid, 256, 0, stream>>>(A, B, C);
    }
}

// Round 5
// 317.553 us; speedup vs baseline: 1.3842x; 1.3842x over previous
//
#include <hip/hip_runtime.h>
#include <hip/hip_bf16.h>

// GemmRS: out[m,n] = sum_{w,k} A[w,m,k]*B[w,n,k]
// A: [8,8192,512] f32, B: [8,1024,512] f32, out: [8192,1024] f32.
// Phase 1: convert A,B -> bf16 in d_ws.
// Phase 2: 32x32x16 bf16 MFMA. Block tile 256x128, 4 waves of 128x64 (4x2 acc).
//   A: LDS double-buffered (64 KB) via global_load_lds w=16, XOR-swizzled.
//   B: direct global->VGPR, double-buffered in TWO STATIC arrays (breg0/breg1)
//      with the K-loop unrolled x2 so every index is compile-time.
//      (R4 lesson: runtime-indexed register arrays are allocated to scratch ->
//       +320 MB WRITE_SIZE and MfmaUtil 11%.)
//   Raw s_barrier + s_waitcnt vmcnt(16) pipeline (no __syncthreads in loop).
//   Grid 256 = 1 block/CU.

#define WS 8
#define MM 8192
#define KK 512
#define NN 1024
#define KTOT (WS * KK)  // 4096
#define BMt 256
#define BNt 128
#define BK 64
#define ITERS (KTOT / BK)  // 64

#define A_ELEMS ((size_t)WS * MM * KK)
#define B_ELEMS ((size_t)WS * NN * KK)
#define WS_NEEDED ((A_ELEMS + B_ELEMS) * 2)

typedef __attribute__((ext_vector_type(8))) short short8;
typedef __attribute__((ext_vector_type(4))) short short4v;
typedef __attribute__((ext_vector_type(4))) float floatx4;
typedef __attribute__((ext_vector_type(16))) float floatx16;

static __device__ inline short f2bf(float f) {
    union { __hip_bfloat16 h; short s; } u;
    u.h = __float2bfloat16(f);  // RNE
    return u.s;
}

static __device__ inline void glds16(const short* g, short* l) {
    __builtin_amdgcn_global_load_lds(
        (const __attribute__((address_space(1))) unsigned int*)(uintptr_t)g,
        (__attribute__((address_space(3))) unsigned int*)(uintptr_t)l,
        16, 0, 0);
}

// ---------------- Phase 1: f32 -> bf16 convert (streaming) ----------------
// 16 elems/thread for ILP: 4x float4 loads, 2x short8 stores.
#define CVT_ABLOCKS 8192   // A: 33.5M / (256*16)
#define CVT_NBLOCKS 9216   // + B: 4.19M / (256*16) = 1024

__global__ __launch_bounds__(256)
void cvt_f32_bf16(const float* __restrict__ A, const float* __restrict__ B,
                  short* __restrict__ Abf, short* __restrict__ Bbf) {
    const float* src;
    short* dst;
    size_t base;
    if (blockIdx.x < CVT_ABLOCKS) {
        src = A; dst = Abf;
        base = ((size_t)blockIdx.x * 256 + threadIdx.x) * 16;
    } else {
        src = B; dst = Bbf;
        base = ((size_t)(blockIdx.x - CVT_ABLOCKS) * 256 + threadIdx.x) * 16;
    }
    float4 v0 = *(const float4*)(src + base);
    float4 v1 = *(const float4*)(src + base + 4);
    float4 v2 = *(const float4*)(src + base + 8);
    float4 v3 = *(const float4*)(src + base + 12);
    short8 o0 = { f2bf(v0.x), f2bf(v0.y), f2bf(v0.z), f2bf(v0.w),
                  f2bf(v1.x), f2bf(v1.y), f2bf(v1.z), f2bf(v1.w) };
    short8 o1 = { f2bf(v2.x), f2bf(v2.y), f2bf(v2.z), f2bf(v2.w),
                  f2bf(v3.x), f2bf(v3.y), f2bf(v3.z), f2bf(v3.w) };
    *(short8*)(dst + base) = o0;
    *(short8*)(dst + base + 8) = o1;
}

// ---------------- Phase 2: 32x32x16 GEMM, A-LDS + B-register pipeline ------
// PIPE_HALF(PB, NB, TN): prefetch tile TN into buffer NB (breg##NB, As[NB]),
// then compute tile in buffer PB. All buffer indices are LITERALS.
#define PIPE_HALF(PB, NB, TN)                                                  \
  {                                                                            \
    const int tn = (TN) & (ITERS - 1);                                         \
    const short* Aw = Abf + (size_t)(tn >> 3) * MM * KK + (tn & 7) * BK;       \
    const short* Bw = Bbf + (size_t)(tn >> 3) * NN * KK + (tn & 7) * BK;       \
    _Pragma("unroll")                                                          \
    for (int j = 0; j < 2; ++j)                                                \
      _Pragma("unroll")                                                        \
      for (int kc = 0; kc < 4; ++kc)                                           \
        breg##NB[j][kc] = *(const short8*)&Bw[(size_t)(nIdx + j * 32) * KK +   \
                                              kc * 16 + khalf * 8];            \
    _Pragma("unroll")                                                          \
    for (int q = 0; q < 8; ++q)                                                \
      glds16(Aw + gA[q], &As[NB][(wid * 8 + q) * 512 + lane * 8]);             \
    asm volatile("s_waitcnt vmcnt(16)" ::: "memory");                          \
    asm volatile("s_barrier" ::: "memory");                                    \
    _Pragma("unroll")                                                          \
    for (int kc = 0; kc < 4; ++kc) {                                           \
      short8 af[4];                                                            \
      _Pragma("unroll")                                                        \
      for (int i = 0; i < 4; ++i) {                                            \
        const int row = wr * 128 + i * 32 + l31;                               \
        const int seg = (kc * 2 + khalf) ^ (lane & 7);                         \
        af[i] = *(const short8*)&As[PB][row * BK + seg * 8];                   \
      }                                                                        \
      _Pragma("unroll")                                                        \
      for (int i = 0; i < 4; ++i)                                              \
        _Pragma("unroll")                                                      \
        for (int j = 0; j < 2; ++j)                                            \
          acc[i][j] = __builtin_amdgcn_mfma_f32_32x32x16_bf16(                 \
              af[i], breg##PB[j][kc], acc[i][j], 0, 0, 0);                     \
    }                                                                          \
    asm volatile("s_barrier" ::: "memory");                                    \
  }

__global__ __launch_bounds__(256, 1)
void gemm_bf16_rs(const short* __restrict__ Abf, const short* __restrict__ Bbf,
                  float* __restrict__ C) {
    __shared__ short As[2][BMt * BK];  // 2 x 32 KB

    const int tid  = threadIdx.x;
    const int lane = tid & 63;
    const int wid  = tid >> 6;
    const int m0 = blockIdx.x * BMt;  // grid.x = 32
    const int n0 = blockIdx.y * BNt;  // grid.y = 8
    const int wr = wid >> 1, wc = wid & 1;  // wave tile: (wr*128, wc*64)
    const int l31   = lane & 31;
    const int khalf = lane >> 5;

    // A staging: chunk = 64 lanes x 16B = 8 rows x 8 segs; XOR swizzle by row&7.
    const int lrow = lane >> 3;
    const int ss   = (lane & 7) ^ lrow;
    size_t gA[8];
#pragma unroll
    for (int q = 0; q < 8; ++q)
        gA[q] = (size_t)(m0 + wid * 64 + q * 8 + lrow) * KK + ss * 8;

    const int nIdx = n0 + wc * 64 + l31;

    floatx16 acc[4][2];
#pragma unroll
    for (int i = 0; i < 4; ++i)
#pragma unroll
        for (int j = 0; j < 2; ++j) acc[i][j] = (floatx16)0.f;

    short8 breg0[2][4], breg1[2][4];  // static names -> stay in VGPRs

    // Prologue: tile 0 (w=0, k=0): B -> breg0, A -> As[0]
#pragma unroll
    for (int j = 0; j < 2; ++j)
#pragma unroll
        for (int kc = 0; kc < 4; ++kc)
            breg0[j][kc] = *(const short8*)&Bbf[(size_t)(nIdx + j * 32) * KK +
                                                kc * 16 + khalf * 8];
#pragma unroll
    for (int q = 0; q < 8; ++q)
        glds16(Abf + gA[q], &As[0][(wid * 8 + q) * 512 + lane * 8]);

#pragma unroll 1
    for (int t = 0; t < ITERS; t += 2) {
        PIPE_HALF(0, 1, t + 1)
        PIPE_HALF(1, 0, t + 2)
    }

    // Epilogue (R4 HW-verified): col=lane&31, row=(r&3)+8*(r>>2)+4*(lane>>5)
#pragma unroll
    for (int i = 0; i < 4; ++i)
#pragma unroll
        for (int j = 0; j < 2; ++j) {
            const int n = n0 + wc * 64 + j * 32 + l31;
            const int mb = m0 + wr * 128 + i * 32 + 4 * khalf;
#pragma unroll
            for (int r = 0; r < 16; ++r) {
                const int m = mb + (r & 3) + 8 * (r >> 2);
                C[(size_t)m * NN + n] = acc[i][j][r];
            }
        }
}

// ---------------- Fallback (fused, ws too small) ----------------
__global__ __launch_bounds__(256, 2)
void gemm_rs_fused(const float* __restrict__ A, const float* __restrict__ B,
                   float* __restrict__ C) {
    __shared__ short Asf[128 * 32];
    __shared__ short Bsf[128 * 32];
    const int tid = threadIdx.x;
    const int m0 = blockIdx.y * 128;
    const int n0 = blockIdx.x * 128;
    const int wid = tid >> 6, lane = tid & 63;
    const int wr = wid >> 1, wc = wid & 1;
    const int lm = lane & 15, quad = lane >> 4;
    floatx4 acc[4][4];
#pragma unroll
    for (int i = 0; i < 4; ++i)
#pragma unroll
        for (int j = 0; j < 4; ++j) acc[i][j] = (floatx4)0.f;
    for (int kt = 0; kt < KTOT; kt += 32) {
        const int w = kt >> 9, kk = kt & (KK - 1);
        const float* Aw = A + (size_t)w * MM * KK;
        const float* Bw = B + (size_t)w * NN * KK;
        __syncthreads();
#pragma unroll
        for (int i = 0; i < 4; ++i) {
            const int idx = i * 256 + tid;
            const int row = idx >> 3;
            const int c4 = (idx & 7) * 4;
            float4 av = *(const float4*)&Aw[(size_t)(m0 + row) * KK + kk + c4];
            float4 bv = *(const float4*)&Bw[(size_t)(n0 + row) * KK + kk + c4];
            short4v a4 = { f2bf(av.x), f2bf(av.y), f2bf(av.z), f2bf(av.w) };
            short4v b4 = { f2bf(bv.x), f2bf(bv.y), f2bf(bv.z), f2bf(bv.w) };
            *(short4v*)&Asf[row * 32 + c4] = a4;
            *(short4v*)&Bsf[row * 32 + c4] = b4;
        }
        __syncthreads();
        short8 af[4], bfr[4];
#pragma unroll
        for (int i = 0; i < 4; ++i)
            af[i] = *(const short8*)&Asf[(wr * 64 + i * 16 + lm) * 32 + quad * 8];
#pragma unroll
        for (int j = 0; j < 4; ++j)
            bfr[j] = *(const short8*)&Bsf[(wc * 64 + j * 16 + lm) * 32 + quad * 8];
#pragma unroll
        for (int i = 0; i < 4; ++i)
#pragma unroll
            for (int j = 0; j < 4; ++j)
                acc[i][j] = __builtin_amdgcn_mfma_f32_16x16x32_bf16(
                    af[i], bfr[j], acc[i][j], 0, 0, 0);
    }
#pragma unroll
    for (int i = 0; i < 4; ++i)
#pragma unroll
        for (int j = 0; j < 4; ++j) {
            const int n = n0 + wc * 64 + j * 16 + lm;
#pragma unroll
            for (int r = 0; r < 4; ++r) {
                const int m = m0 + wr * 64 + i * 16 + quad * 4 + r;
                C[(size_t)m * NN + n] = acc[i][j][r];
            }
        }
}

extern "C" void kernel_launch(void* const* d_in, const int* in_sizes, int n_in,
                              void* d_out, int out_size, void* d_ws, size_t ws_size,
                              hipStream_t stream) {
    const float* A = (const float*)d_in[0];  // [8,8192,512]
    const float* B = (const float*)d_in[1];  // [8,1024,512]
    float* C = (float*)d_out;                // [8192,1024]

    if (ws_size >= WS_NEEDED) {
        short* Abf = (short*)d_ws;
        short* Bbf = Abf + A_ELEMS;
        cvt_f32_bf16<<<CVT_NBLOCKS, 256, 0, stream>>>(A, B, Abf, Bbf);
        dim3 grid(MM / BMt, NN / BNt);  // (32, 8) = 256 blocks, 1/CU
        gemm_bf16_rs<<<grid, 256, 0, stream>>>(Abf, Bbf, C);
    } else {
        dim3 grid(NN / 128, MM / 128);
        gemm_rs_fused<<<grid, 256, 0, stream>>>(A, B, C);
    }
}